// Round 9
// baseline (144.761 us; speedup 1.0000x reference)
//
#include <hip/hip_runtime.h>
#include <hip/hip_bf16.h>
#include <math.h>

#define EPSV 1e-6f
#define LAMBDAV 1e-3f
#define LN_2PI 1.8378770664093453f

__device__ __forceinline__ float bflo(unsigned int u) {
    union { unsigned int i; float f; } x; x.i = u << 16; return x.f;
}
__device__ __forceinline__ float bfhi(unsigned int u) {
    union { unsigned int i; float f; } x; x.i = u & 0xffff0000u; return x.f;
}

// Kernel 1: v[nl, i2, cq] bf16. Block = 512 threads = one (c,q) each; only 16
// w values live per thread (register-resident, no AGPR/scratch round-trip).
// grid = (288 i2, chunks of 64 positions).
__global__ __launch_bounds__(512)
void conv_v_kernel(const float* __restrict__ x, const float* __restrict__ w,
                   __hip_bfloat16* __restrict__ vout, int n0, int cnt)
{
    __shared__ float pv[64 * 16];   // 4 KB: 64 positions x 16 p

    const int i2  = blockIdx.x;
    const int kb0 = blockIdx.y * 64;
    const int tid = threadIdx.x;
    const int c1 = tid >> 4, q1 = tid & 15;   // c1 0..31, q1 0..15

    // w[i2][c1][p][q1] -> 16 regs (lanes vary q1 -> 16x4B coalesced segments)
    const float* wp = w + (size_t)i2 * 8192 + c1 * 256 + q1;
    float wr[16];
    #pragma unroll
    for (int p = 0; p < 16; ++p) wr[p] = wp[p * 16];

    // gather 64 positions x 16 p into LDS (2 elements/thread)
    #pragma unroll
    for (int u = 0; u < 2; ++u) {
        int idx = u * 512 + tid;
        int k = idx >> 4, p = idx & 15;
        // reference reshape scramble: g=i2*16+p; k2=g>>9; c2=g&511; f=k2*544+c2=ci*9+kk
        int e  = i2 * 16 + p;
        int k2 = e >> 9, c2 = e & 511;
        int f  = k2 * 544 + c2;
        int ci = f / 9, kk = f - ci * 9;
        int nn = n0 + kb0 + k;
        float val = 0.f;
        if (kb0 + k < cnt) {
            int bi = nn >> 6, oi = (nn >> 3) & 7, oj = nn & 7;
            int row = 2 * oi + kk / 3 - 1;
            int col = 2 * oj + (kk - (kk / 3) * 3) - 1;
            if ((unsigned)row < 16u && (unsigned)col < 16u)
                val = x[((bi * 16 + row) * 16 + col) * 544 + ci];
        }
        pv[k * 16 + p] = val;
    }
    __syncthreads();

    const int kmax = min(64, cnt - kb0);
    #pragma unroll 4
    for (int k = 0; k < kmax; ++k) {
        const float4 pa = *(const float4*)&pv[k * 16];
        const float4 pb = *(const float4*)&pv[k * 16 + 4];
        const float4 pc = *(const float4*)&pv[k * 16 + 8];
        const float4 pd = *(const float4*)&pv[k * 16 + 12];
        float acc;
        acc  = pa.x * wr[0]  + pa.y * wr[1]  + pa.z * wr[2]  + pa.w * wr[3];
        acc += pb.x * wr[4]  + pb.y * wr[5]  + pb.z * wr[6]  + pb.w * wr[7];
        acc += pc.x * wr[8]  + pc.y * wr[9]  + pc.z * wr[10] + pc.w * wr[11];
        acc += pd.x * wr[12] + pd.y * wr[13] + pd.z * wr[14] + pd.w * wr[15];
        vout[((size_t)(kb0 + k) * 288 + i2) * 512 + tid] = __float2bfloat16(acc);
    }
}

// Kernel 2: EM routing, fused single sweep, q split across wave halves.
// Block = 1024 = 16 waves. Lane = (qh = lane>>5, c = lane&31); each lane owns
// 8 q's (one uint4 row read). Wave w handles rows {w + 16k}, k<18.
// (__launch_bounds__(1024,4) -> 128-VGPR cap, no scratch spills.)
__global__ __launch_bounds__(1024, 4)
void em_routing_kernel(const float* __restrict__ x,
                       const unsigned short* __restrict__ v,   // [n][i][cq] bf16
                       const float* __restrict__ beta_u,
                       const float* __restrict__ beta_a,
                       float* __restrict__ out, int n0)
{
    __shared__ float fct_s[288];            // a/(a+eps)
    __shared__ float red_s[16 * 64 * 17];   // [wave][lane][s0|s1[8]|s2[8]] 69.6 KB
    __shared__ float mu_s[32 * 17];
    __shared__ float i2ss_s[32 * 17];
    __shared__ float hlog_s[32 * 17];
    __shared__ float rsum_s[32];
    __shared__ float aout_s[32];
    __shared__ float kc_s[32];

    const int n   = n0 + blockIdx.x;
    const int tid = threadIdx.x;
    const int bi = n >> 6, oi = (n >> 3) & 7, oj = n & 7;

    if (tid < 288) {
        // a_in gather: c2 in [512,544)
        int k2 = tid >> 5;
        int c2 = 512 + (tid & 31);
        int f  = k2 * 544 + c2;
        int ci = f / 9;
        int kk = f - ci * 9;
        int row = 2 * oi + kk / 3 - 1;
        int col = 2 * oj + (kk - (kk / 3) * 3) - 1;
        float a = 0.f;
        if ((unsigned)row < 16u && (unsigned)col < 16u)
            a = x[((bi * 16 + row) * 16 + col) * 544 + ci];
        fct_s[tid] = a / (a + EPSV);   // sum_c r*a == a -> rr = softmax * fct
    }
    __syncthreads();

    const unsigned short* vb = v + (size_t)blockIdx.x * 288 * 512;
    const int wv   = tid >> 6;      // wave 0..15
    const int lane = tid & 63;
    const int c    = lane & 31;
    const int qh   = lane >> 5;     // q-half 0/1
    const int qb   = qh * 8;

    for (int t = 0; t < 3; ++t) {
        float mu8[8], is8[8], kcv = 0.f;
        if (t > 0) {
            #pragma unroll
            for (int j = 0; j < 8; ++j) {
                mu8[j] = mu_s[c * 17 + qb + j];
                is8[j] = i2ss_s[c * 17 + qb + j];
            }
            kcv = kc_s[c];
        }

        float s0 = 0.f, s1[8], s2[8];
        #pragma unroll
        for (int j = 0; j < 8; ++j) { s1[j] = 0.f; s2[j] = 0.f; }

        #pragma unroll 2
        for (int k = 0; k < 18; ++k) {
            const int i = k * 16 + wv;
            uint4 u = *(const uint4*)(vb + (size_t)i * 512 + c * 16 + qb);
            float vv[8];
            vv[0] = bflo(u.x); vv[1] = bfhi(u.x);
            vv[2] = bflo(u.y); vv[3] = bfhi(u.y);
            vv[4] = bflo(u.z); vv[5] = bfhi(u.z);
            vv[6] = bflo(u.w); vv[7] = bfhi(u.w);

            float rrv;
            if (t == 0) {
                rrv = fct_s[i] * 0.03125f;   // uniform r
            } else {
                float pacc = 0.f;
                #pragma unroll
                for (int j = 0; j < 8; ++j) {
                    float d = vv[j] - mu8[j];
                    pacc += d * d * is8[j];
                }
                pacc += __shfl_xor(pacc, 32, 64);    // combine q-halves
                float acc = kcv - pacc;
                // softmax over c (width-32; both halves identical)
                float mx = acc;
                mx = fmaxf(mx, __shfl_xor(mx, 1, 32));
                mx = fmaxf(mx, __shfl_xor(mx, 2, 32));
                mx = fmaxf(mx, __shfl_xor(mx, 4, 32));
                mx = fmaxf(mx, __shfl_xor(mx, 8, 32));
                mx = fmaxf(mx, __shfl_xor(mx, 16, 32));
                float e = expf(acc - mx);
                float se = e;
                se += __shfl_xor(se, 1, 32);
                se += __shfl_xor(se, 2, 32);
                se += __shfl_xor(se, 4, 32);
                se += __shfl_xor(se, 8, 32);
                se += __shfl_xor(se, 16, 32);
                rrv = (e / se) * fct_s[i];
            }

            s0 += rrv;
            #pragma unroll
            for (int j = 0; j < 8; ++j) {
                s1[j] += rrv * vv[j];
                s2[j] += rrv * vv[j] * vv[j];
            }
        }

        // per-wave partials -> LDS (stride 17: 2-way bank alias = free)
        {
            float* dst = &red_s[(wv * 64 + lane) * 17];
            dst[0] = s0;
            #pragma unroll
            for (int j = 0; j < 8; ++j) { dst[1 + j] = s1[j]; dst[9 + j] = s2[j]; }
        }
        __syncthreads();

        // final 16-way reduce + mu/sigma (thread = (c2,q2))
        if (tid < 512) {
            int c2 = tid >> 4, q2 = tid & 15;
            int qh2 = q2 >> 3, j2 = q2 & 7;
            float S0 = 0.f, S1 = 0.f, S2 = 0.f;
            #pragma unroll
            for (int wvi = 0; wvi < 16; ++wvi) {
                S0 += red_s[(wvi * 64 + c2) * 17];
                const float* sp = &red_s[(wvi * 64 + qh2 * 32 + c2) * 17];
                S1 += sp[1 + j2];
                S2 += sp[9 + j2];
            }
            if (q2 == 0) rsum_s[c2] = S0;
            float invr = 1.0f / (S0 + EPSV);
            float w0  = S0 * invr;
            float m   = S1 * invr;
            float s2p = S2 * invr;
            float sig = s2p - m * m * (2.0f - w0);   // == sum coeff*(v-mu)^2
            sig = fmaxf(sig + EPSV, 1e-4f);
            float hl = 0.5f * logf(sig);
            mu_s[c2 * 17 + q2]   = m;
            hlog_s[c2 * 17 + q2] = hl;
            i2ss_s[c2 * 17 + q2] = 1.0f / (2.0f * sig);
        }
        __syncthreads();

        // a_out + per-c ln_p constant
        if (tid < 32) {
            float cs = 0.f, shl = 0.f;
            float bu = beta_u[tid];
            #pragma unroll
            for (int q = 0; q < 16; ++q) { float hl = hlog_s[tid * 17 + q]; shl += hl; cs += bu + hl; }
            cs *= rsum_s[tid];
            float arg = LAMBDAV * (beta_a[tid] - cs);
            float ao  = 1.0f / (1.0f + expf(-arg));
            ao = fminf(fmaxf(ao, 1e-4f), 1.0f - 1e-4f);
            aout_s[tid] = ao;
            kc_s[tid]   = logf(ao + EPSV) - shl - 8.0f * LN_2PI;
        }
        __syncthreads();
    }

    // epilogue (fp32): p_out [0,65536) | a_out [65536,69632) | out [69632,139264)
    if (tid < 512) {
        int c2 = tid >> 4, q2 = tid & 15;
        float mu = mu_s[c2 * 17 + q2];
        if (isnan(mu)) mu = 0.f;
        mu = fminf(fmaxf(mu, -10000.f), 10000.f);
        out[(size_t)n * 512 + tid] = mu;
        out[69632 + (size_t)n * 544 + tid] = mu;
        if (tid < 32) {
            float ao = aout_s[tid];
            if (isnan(ao)) ao = 0.5f;
            out[65536 + n * 32 + tid] = ao;
            out[69632 + n * 544 + 512 + tid] = ao;
        }
    }
}

extern "C" void kernel_launch(void* const* d_in, const int* in_sizes, int n_in,
                              void* d_out, int out_size, void* d_ws, size_t ws_size,
                              hipStream_t stream) {
    const float* x  = (const float*)d_in[0];
    const float* w  = (const float*)d_in[1];
    const float* bu = (const float*)d_in[2];
    const float* ba = (const float*)d_in[3];
    float* out = (float*)d_out;
    __hip_bfloat16* v = (__hip_bfloat16*)d_ws;  // 128*288*512 bf16 = 37.7 MB

    const size_t per_n = (size_t)288 * 512 * sizeof(__hip_bfloat16); // 294912 B
    int CN = (int)(ws_size / per_n);
    if (CN < 1)   CN = 1;
    if (CN > 128) CN = 128;

    for (int ncur = 0; ncur < 128; ncur += CN) {
        int cnt = (128 - ncur < CN) ? (128 - ncur) : CN;
        conv_v_kernel<<<dim3(288, (cnt + 63) / 64), dim3(512), 0, stream>>>(
            x, w, v, ncur, cnt);
        em_routing_kernel<<<dim3(cnt), dim3(1024), 0, stream>>>(
            x, (const unsigned short*)v, bu, ba, out, ncur);
    }
}